// Round 11
// baseline (70.554 us; speedup 1.0000x reference)
//
#include <hip/hip_runtime.h>

#define NB 4
#define NS 1024
#define NH 16
#define ND 64

typedef __attribute__((ext_vector_type(8))) short bf16x8;
typedef __attribute__((ext_vector_type(4))) float f32x4;

static __device__ __forceinline__ short f2bf(float x) {
  __bf16 h = (__bf16)x;
  return __builtin_bit_cast(short, h);
}
static __device__ __forceinline__ float bf2f(short s) {
  unsigned u = ((unsigned)(unsigned short)s) << 16;
  return __builtin_bit_cast(float, u);
}

__global__ __launch_bounds__(512, 2)
void fsa_fwd(const float* __restrict__ qkv,
             const float* __restrict__ bias,
             float* __restrict__ out)
{
  // XCD-chunked swizzle, batch-fastest logical order. grid=512, bijective.
  const int hw = blockIdx.x;
  const int lg = ((hw & 7) << 6) | (hw >> 3);
  const int b  = lg & 3;
  const int qt = (lg >> 2) & 7;       // 8 q-tiles of 128 rows
  const int h  = lg >> 5;

  const int tid  = threadIdx.x;
  const int w    = tid >> 6;          // wave 0..7
  const int lane = tid & 63;
  const int lo   = lane & 15;
  const int hi   = lane >> 4;
  const int q0   = qt * 128;

  __shared__ __attribute__((aligned(16))) short Ksh[128 * 64];   // [t][d] XOR-swizzled rows (16 KB)
  __shared__ __attribute__((aligned(16))) short VTsh[64 * 128];  // [d][t] packed-pair XOR-swizzled (16 KB)
  __shared__ __attribute__((aligned(16))) short Psh[8][16 * 128];// per-wave P strip (32 KB)

  // ---- Q fragments (A-operand), pre-scaled by 1/8; wave owns rows q0+w*16..+15 ----
  bf16x8 qf[2];
  {
    const int qs = q0 + w * 16 + lo;
    const float* qp = qkv + ((size_t)(b * NS + qs) * 3) * (NH * ND) + h * ND + hi * 8;
    #pragma unroll
    for (int f = 0; f < 2; ++f) {
      float4 x0 = *(const float4*)(qp + f * 32);
      float4 x1 = *(const float4*)(qp + f * 32 + 4);
      float v[8] = {x0.x, x0.y, x0.z, x0.w, x1.x, x1.y, x1.z, x1.w};
      #pragma unroll
      for (int j = 0; j < 8; ++j) qf[f][j] = f2bf(v[j] * 0.125f);
    }
  }

  const size_t tstr = 3 * NH * ND;  // 3072 floats per s-step
  const float* kg = qkv + (size_t)b * NS * tstr + 1 * NH * ND + h * ND;
  const float* vg = qkv + (size_t)b * NS * tstr + 2 * NH * ND + h * ND;

  // staging split across 512 threads, 128-row KV tile
  const int krow = tid >> 2;          // 0..127
  const int kd   = (tid & 3) * 16;    // 16 floats per thread
  const int vrow = (tid & 63) * 2;    // t pair 0..126
  const int vd   = (tid >> 6) * 8;    // 8 d's per wave-slice

  const float* bb = bias + (size_t)h * NS * NS + (size_t)(q0 + w * 16 + hi * 4) * NS + lo;

  float psum[4] = {0.f, 0.f, 0.f, 0.f};
  f32x4 oacc[4];
  #pragma unroll
  for (int dt = 0; dt < 4; ++dt) { f32x4 z = {0.f, 0.f, 0.f, 0.f}; oacc[dt] = z; }

  #pragma unroll 1
  for (int it = 0; it < 8; ++it) {
    const int t0 = it * 128;

    // ---- load + convert K tile rows (16 f32 -> 2 bf16x8 per thread) ----
    bf16x8 w0, w1;
    {
      const float* src = kg + (size_t)(t0 + krow) * tstr + kd;
      float4 a = ((const float4*)src)[0];
      float4 c = ((const float4*)src)[1];
      float4 e = ((const float4*)src)[2];
      float4 g = ((const float4*)src)[3];
      float v[16] = {a.x,a.y,a.z,a.w, c.x,c.y,c.z,c.w, e.x,e.y,e.z,e.w, g.x,g.y,g.z,g.w};
      #pragma unroll
      for (int j = 0; j < 8; ++j) { w0[j] = f2bf(v[j]); w1[j] = f2bf(v[8 + j]); }
    }
    // ---- load + convert V tile (2 t-rows x 8 d, packed pairs) ----
    unsigned vpk[8];
    {
      const float* s0 = vg + (size_t)(t0 + vrow) * tstr + vd;
      const float* s1 = s0 + tstr;
      float4 a0 = ((const float4*)s0)[0], a1 = ((const float4*)s0)[1];
      float4 b0 = ((const float4*)s1)[0], b1 = ((const float4*)s1)[1];
      float r0[8] = {a0.x,a0.y,a0.z,a0.w, a1.x,a1.y,a1.z,a1.w};
      float r1[8] = {b0.x,b0.y,b0.z,b0.w, b1.x,b1.y,b1.z,b1.w};
      #pragma unroll
      for (int j = 0; j < 8; ++j)
        vpk[j] = (unsigned)(unsigned short)f2bf(r0[j]) |
                 ((unsigned)(unsigned short)f2bf(r1[j]) << 16);
    }

    __syncthreads();  // prior iteration's K/V LDS reads complete

    {
      const int base = krow * 64 + kd;
      const int sw = (krow & 7) << 3;
      *(bf16x8*)&Ksh[(base    ) ^ sw] = w0;
      *(bf16x8*)&Ksh[(base + 8) ^ sw] = w1;
    }
    {
      unsigned* vt32 = (unsigned*)VTsh;   // row stride 64 u32
      #pragma unroll
      for (int j = 0; j < 8; ++j) {
        const int R = vd + j;
        vt32[R * 64 + ((vrow >> 1) ^ ((R & 7) << 2))] = vpk[j];
      }
    }

    // ---- bias for this tile (issued before barrier; latency overlaps it) ----
    float br[4][8];
    #pragma unroll
    for (int r = 0; r < 4; ++r)
      #pragma unroll
      for (int tt = 0; tt < 8; ++tt)
        br[r][tt] = bb[(size_t)r * NS + t0 + tt * 16];

    __syncthreads();  // K/V tile visible in LDS

    __builtin_amdgcn_s_setprio(1);
    // ---- QK^T: 8 t-subtiles, acc init = bias - 8 ----
    f32x4 sacc[8];
    #pragma unroll
    for (int tt = 0; tt < 8; ++tt) {
      f32x4 sb;
      #pragma unroll
      for (int r = 0; r < 4; ++r) sb[r] = br[r][tt] - 8.f;
      const int kr = tt * 16 + lo;
      const int ksw = (kr & 7) << 3;
      bf16x8 k0 = *(const bf16x8*)&Ksh[(kr * 64      + hi * 8) ^ ksw];
      bf16x8 k1 = *(const bf16x8*)&Ksh[(kr * 64 + 32 + hi * 8) ^ ksw];
      sb = __builtin_amdgcn_mfma_f32_16x16x32_bf16(qf[0], k0, sb, 0, 0, 0);
      sb = __builtin_amdgcn_mfma_f32_16x16x32_bf16(qf[1], k1, sb, 0, 0, 0);
      sacc[tt] = sb;
    }

    // ---- P = exp(s), per-lane psum, per-wave P strip ----
    short* pw = Psh[w];
    #pragma unroll
    for (int r = 0; r < 4; ++r) {
      const int row = hi * 4 + r;
      const int sw = (row & 7) << 3;
      #pragma unroll
      for (int tt = 0; tt < 8; ++tt) {
        float p = __expf(sacc[tt][r]);
        short pb = f2bf(p);
        psum[r] += bf2f(pb);
        pw[row * 128 + ((tt * 16 + lo) ^ sw)] = pb;
      }
    }
    asm volatile("s_waitcnt lgkmcnt(0)" ::: "memory");

    // ---- PV: 4 t-groups of 32 ----
    bf16x8 pf[4];
    {
      const int psw = (lo & 7) << 3;
      #pragma unroll
      for (int g = 0; g < 4; ++g)
        pf[g] = *(const bf16x8*)&pw[lo * 128 + ((g * 32 + hi * 8) ^ psw)];
    }
    #pragma unroll
    for (int dt = 0; dt < 4; ++dt) {
      const int vr = dt * 16 + lo;
      const int vsw = (vr & 7) << 4;   // short-index XOR = u32 ((R&7)<<2)*2... see below
      // VT row vr: shorts at t-col g*32 + hi*8, u32 idx = g*16 + hi*4, XOR (vr&7)<<2 (u32)
      const unsigned* vtrow = (const unsigned*)VTsh + (size_t)vr * 64;
      #pragma unroll
      for (int g = 0; g < 4; ++g) {
        bf16x8 vv = *(const bf16x8*)&vtrow[(g * 16 + hi * 4) ^ ((vr & 7) << 2)];
        oacc[dt] = __builtin_amdgcn_mfma_f32_16x16x32_bf16(pf[g], vv, oacc[dt], 0, 0, 0);
      }
    }
    __builtin_amdgcn_s_setprio(0);
  }

  // ---- final row-sum reduction (once) ----
  #pragma unroll
  for (int r = 0; r < 4; ++r) {
    psum[r] += __shfl_xor(psum[r], 1, 64);
    psum[r] += __shfl_xor(psum[r], 2, 64);
    psum[r] += __shfl_xor(psum[r], 4, 64);
    psum[r] += __shfl_xor(psum[r], 8, 64);
  }

  // ---- epilogue: out[b][s][h][d] ----
  float* ob = out + ((size_t)(b * NS + q0 + w * 16 + hi * 4) * NH + h) * ND + lo;
  #pragma unroll
  for (int r = 0; r < 4; ++r) {
    float inv = 1.f / psum[r];
    #pragma unroll
    for (int dt = 0; dt < 4; ++dt)
      ob[(size_t)r * NH * ND + dt * 16] = oacc[dt][r] * inv;
  }
}

extern "C" void kernel_launch(void* const* d_in, const int* in_sizes, int n_in,
                              void* d_out, int out_size, void* d_ws, size_t ws_size,
                              hipStream_t stream) {
  const float* qkv  = (const float*)d_in[0];
  const float* bias = (const float*)d_in[1];
  float* out = (float*)d_out;
  dim3 grid(NB * NH * (NS / 128));
  fsa_fwd<<<grid, 512, 0, stream>>>(qkv, bias, out);
}

// Round 12
// 64.666 us; speedup vs baseline: 1.0911x; 1.0911x over previous
//
#include <hip/hip_runtime.h>
#include <cmath>

#define NB 4
#define NS 1024
#define NH 16
#define ND 64

typedef __attribute__((ext_vector_type(8))) short bf16x8;
typedef __attribute__((ext_vector_type(4))) float f32x4;

static __device__ __forceinline__ short f2bf(float x) {
  __bf16 h = (__bf16)x;
  return __builtin_bit_cast(short, h);
}

static __device__ __forceinline__ float fast_exp2(float x) {
#if __has_builtin(__builtin_amdgcn_exp2f)
  return __builtin_amdgcn_exp2f(x);   // v_exp_f32 with compiler hazard handling (R9-proven)
#else
  return exp2f(x);
#endif
}

#define LOG2E 1.44269504f

__global__ __launch_bounds__(512, 2)
void fsa_fwd(const float* __restrict__ qkv,
             const float* __restrict__ bias,
             float* __restrict__ out)
{
  // XCD-chunked swizzle, batch-fastest logical order. grid=512, bijective.
  const int hw = blockIdx.x;
  const int lg = ((hw & 7) << 6) | (hw >> 3);
  const int b  = lg & 3;
  const int qt = (lg >> 2) & 7;       // 8 q-tiles of 128 rows
  const int h  = lg >> 5;

  const int tid  = threadIdx.x;
  const int w    = tid >> 6;          // wave 0..7
  const int lane = tid & 63;
  const int lo   = lane & 15;
  const int hi   = lane >> 4;
  const int q0   = qt * 128;

  __shared__ __attribute__((aligned(16))) short Ksh[64 * 64];   // [t][d] XOR-swizzled rows
  __shared__ __attribute__((aligned(16))) short VTsh[64 * 64];  // [d][t] packed-pair XOR-swizzled
  __shared__ __attribute__((aligned(16))) short Psh[8][16 * 64];// per-wave P strip

  // ---- Q fragments (A-operand), pre-scaled by 0.125*log2e ----
  bf16x8 qf[2];
  {
    const int qs = q0 + w * 16 + lo;
    const float* qp = qkv + ((size_t)(b * NS + qs) * 3) * (NH * ND) + h * ND + hi * 8;
    #pragma unroll
    for (int f = 0; f < 2; ++f) {
      float4 x0 = *(const float4*)(qp + f * 32);
      float4 x1 = *(const float4*)(qp + f * 32 + 4);
      float v[8] = {x0.x, x0.y, x0.z, x0.w, x1.x, x1.y, x1.z, x1.w};
      #pragma unroll
      for (int j = 0; j < 8; ++j) qf[f][j] = f2bf(v[j] * (0.125f * LOG2E));
    }
  }

  const size_t tstr = 3 * NH * ND;  // 3072 floats per s-step
  const float* kg = qkv + (size_t)b * NS * tstr + 1 * NH * ND + h * ND;
  const float* vg = qkv + (size_t)b * NS * tstr + 2 * NH * ND + h * ND;

  // staging split across 512 threads (R10 geometry)
  const int krow = tid >> 3;          // 0..63
  const int kd   = (tid & 7) * 8;     // 8 floats per thread
  const int vrow = (tid & 31) * 2;    // t pair
  const int vd   = (tid >> 5) * 4;    // 4 d's per thread

  const float* bb = bias + (size_t)h * NS * NS + (size_t)(q0 + w * 16 + hi * 4) * NS + lo;

  float psum[4] = {0.f, 0.f, 0.f, 0.f};
  f32x4 oacc[4];
  #pragma unroll
  for (int dt = 0; dt < 4; ++dt) { f32x4 z = {0.f, 0.f, 0.f, 0.f}; oacc[dt] = z; }

  // prefetch regs: K (8 f32), V (2 rows x 4 d), bias (16) — tile t entering iter t
  float4 kpa, kpb, vpa, vpb;
  float br[4][4];

#define LOAD_KV(T0) do { \
    const float* src_ = kg + (size_t)((T0) + krow) * tstr + kd; \
    kpa = ((const float4*)src_)[0]; \
    kpb = ((const float4*)src_)[1]; \
    const float* s0_ = vg + (size_t)((T0) + vrow) * tstr + vd; \
    vpa = *(const float4*)s0_; \
    vpb = *(const float4*)(s0_ + tstr); \
  } while (0)

#define LOAD_BIAS(T0) do { \
    _Pragma("unroll") \
    for (int r_ = 0; r_ < 4; ++r_) { \
      _Pragma("unroll") \
      for (int tt_ = 0; tt_ < 4; ++tt_) \
        br[r_][tt_] = bb[(size_t)r_ * NS + (T0) + tt_ * 16]; \
    } \
  } while (0)

#define STAGE() do { \
    bf16x8 w0_; \
    { \
      float v_[8] = {kpa.x,kpa.y,kpa.z,kpa.w, kpb.x,kpb.y,kpb.z,kpb.w}; \
      _Pragma("unroll") \
      for (int j_ = 0; j_ < 8; ++j_) w0_[j_] = f2bf(v_[j_]); \
    } \
    { \
      const int base_ = krow * 64 + kd; \
      const int sw_ = (krow & 7) << 3; \
      *(bf16x8*)&Ksh[base_ ^ sw_] = w0_; \
    } \
    { \
      float r0_[4] = {vpa.x,vpa.y,vpa.z,vpa.w}; \
      float r1_[4] = {vpb.x,vpb.y,vpb.z,vpb.w}; \
      unsigned* vt_ = (unsigned*)VTsh; \
      _Pragma("unroll") \
      for (int j_ = 0; j_ < 4; ++j_) { \
        unsigned pk_ = (unsigned)(unsigned short)f2bf(r0_[j_]) | \
                       ((unsigned)(unsigned short)f2bf(r1_[j_]) << 16); \
        const int R_ = vd + j_; \
        vt_[R_ * 32 + ((vrow >> 1) ^ ((R_ & 7) << 2))] = pk_; \
      } \
    } \
  } while (0)

  // ---- prologue: tile-0 K/V + bias into regs ----
  LOAD_KV(0);
  LOAD_BIAS(0);

  #pragma unroll 1
  for (int it = 0; it < 16; ++it) {
    __syncthreads();                      // prior iteration's LDS reads complete
    STAGE();                              // cvt + ds_write tile `it` (prefetched regs)
    if (it < 15) LOAD_KV((it + 1) * 64);  // next tile flies under this iteration's compute
    __syncthreads();                      // tile `it` visible in LDS

    // ---- S acc init = (bias - 8) * log2e ----
    f32x4 sacc[4];
    #pragma unroll
    for (int tt = 0; tt < 4; ++tt) {
      #pragma unroll
      for (int r = 0; r < 4; ++r)
        sacc[tt][r] = br[r][tt] * LOG2E - (8.f * LOG2E);
    }
    if (it < 15) LOAD_BIAS((it + 1) * 64);  // bias(t+1) flies under compute

    __builtin_amdgcn_s_setprio(1);
    // ---- QK^T: 8 MFMAs (R10 body) ----
    #pragma unroll
    for (int tt = 0; tt < 4; ++tt) {
      const int kr = tt * 16 + lo;
      const int ksw = (kr & 7) << 3;
      bf16x8 k0 = *(const bf16x8*)&Ksh[(kr * 64      + hi * 8) ^ ksw];
      bf16x8 k1 = *(const bf16x8*)&Ksh[(kr * 64 + 32 + hi * 8) ^ ksw];
      sacc[tt] = __builtin_amdgcn_mfma_f32_16x16x32_bf16(qf[0], k0, sacc[tt], 0, 0, 0);
      sacc[tt] = __builtin_amdgcn_mfma_f32_16x16x32_bf16(qf[1], k1, sacc[tt], 0, 0, 0);
    }

    // ---- P = exp2(s), per-lane f32 psum, per-wave P strip ----
    short* pw = Psh[w];
    #pragma unroll
    for (int r = 0; r < 4; ++r) {
      const int row = hi * 4 + r;
      const int sw = (row & 7) << 3;
      #pragma unroll
      for (int tt = 0; tt < 4; ++tt) {
        float p = fast_exp2(sacc[tt][r]);
        psum[r] += p;
        pw[row * 64 + ((tt * 16 + lo) ^ sw)] = f2bf(p);
      }
    }
    asm volatile("s_waitcnt lgkmcnt(0)" ::: "memory");

    // ---- PV ----
    bf16x8 pf0, pf1;
    {
      const int psw = (lo & 7) << 3;
      pf0 = *(const bf16x8*)&pw[lo * 64 + ((     hi * 8) ^ psw)];
      pf1 = *(const bf16x8*)&pw[lo * 64 + ((32 + hi * 8) ^ psw)];
    }
    #pragma unroll
    for (int dt = 0; dt < 4; ++dt) {
      const int vr = dt * 16 + lo;
      const int vsw = (vr & 7) << 3;
      bf16x8 v0 = *(const bf16x8*)&VTsh[vr * 64 + ((     hi * 8) ^ vsw)];
      bf16x8 v1 = *(const bf16x8*)&VTsh[vr * 64 + ((32 + hi * 8) ^ vsw)];
      oacc[dt] = __builtin_amdgcn_mfma_f32_16x16x32_bf16(pf0, v0, oacc[dt], 0, 0, 0);
      oacc[dt] = __builtin_amdgcn_mfma_f32_16x16x32_bf16(pf1, v1, oacc[dt], 0, 0, 0);
    }
    __builtin_amdgcn_s_setprio(0);
  }

#undef STAGE
#undef LOAD_BIAS
#undef LOAD_KV

  // ---- final row-sum reduction (once) ----
  #pragma unroll
  for (int r = 0; r < 4; ++r) {
    psum[r] += __shfl_xor(psum[r], 1, 64);
    psum[r] += __shfl_xor(psum[r], 2, 64);
    psum[r] += __shfl_xor(psum[r], 4, 64);
    psum[r] += __shfl_xor(psum[r], 8, 64);
  }

  // ---- epilogue: out[b][s][h][d] ----
  float* ob = out + ((size_t)(b * NS + q0 + w * 16 + hi * 4) * NH + h) * ND + lo;
  #pragma unroll
  for (int r = 0; r < 4; ++r) {
    float inv = 1.f / psum[r];
    #pragma unroll
    for (int dt = 0; dt < 4; ++dt)
      ob[(size_t)r * NH * ND + dt * 16] = oacc[dt][r] * inv;
  }
}

extern "C" void kernel_launch(void* const* d_in, const int* in_sizes, int n_in,
                              void* d_out, int out_size, void* d_ws, size_t ws_size,
                              hipStream_t stream) {
  const float* qkv  = (const float*)d_in[0];
  const float* bias = (const float*)d_in[1];
  float* out = (float*)d_out;
  dim3 grid(NB * NH * (NS / 128));
  fsa_fwd<<<grid, 512, 0, stream>>>(qkv, bias, out);
}